// Round 1
// baseline (631.212 us; speedup 1.0000x reference)
//
#include <hip/hip_runtime.h>
#include <hip/hip_bf16.h>

// ShiftWindowMSA fused pipeline for MI355X (gfx950).
// Stages: prep (weight transpose->bf16, rel-pos bias table), gemm_qkv
// (gather+convert+GEMM -> k,q row-major / v transposed, bf16), attn
// (per-(window,head) wave: QK^T, bias+mask, softmax, PV), gemm_proj
// (GEMM + bias + inverse shift-window scatter, fp32 out).

typedef __attribute__((ext_vector_type(8))) short short8;
typedef __attribute__((ext_vector_type(4))) short short4v;
typedef __attribute__((ext_vector_type(4))) float floatx4;

#define MFMA16(a, b, c) __builtin_amdgcn_mfma_f32_16x16x32_bf16(a, b, c, 0, 0, 0)

__device__ __forceinline__ short f2bf(float f) {
    __hip_bfloat16 h = __float2bfloat16(f);
    return *reinterpret_cast<short*>(&h);
}

// ---------------- prep kernels ----------------

// Wt[1152][384] bf16: rows 0..767 = columns of W_qkv (384x768); 768.. = columns of W_skip (384x384)
__global__ __launch_bounds__(256) void prep_wt(const float* __restrict__ Wqkv,
                                               const float* __restrict__ Wskip,
                                               short* __restrict__ Wt) {
    int tid = blockIdx.x * 256 + threadIdx.x;  // 384*144 = 55296
    if (tid >= 384 * 144) return;
    int k = tid / 144;
    int n8 = (tid % 144) * 8;
#pragma unroll
    for (int e = 0; e < 8; e++) {
        int n = n8 + e;
        float v = (n < 768) ? Wqkv[k * 768 + n] : Wskip[k * 384 + (n - 768)];
        Wt[(size_t)n * 384 + k] = f2bf(v);
    }
}

__global__ __launch_bounds__(256) void prep_wtp(const float* __restrict__ Wproj,
                                                short* __restrict__ WtP) {
    int tid = blockIdx.x * 256 + threadIdx.x;  // 384*48 = 18432
    if (tid >= 384 * 48) return;
    int k = tid / 48;
    int n8 = (tid % 48) * 8;
#pragma unroll
    for (int e = 0; e < 8; e++) {
        int n = n8 + e;
        WtP[(size_t)n * 384 + k] = f2bf(Wproj[k * 384 + n]);
    }
}

// bias64[h][i][kk] = rpb_table[r(i) + r(63-kk)][h],  r(t) = 15*(t>>3) + (t&7)
__global__ __launch_bounds__(256) void prep_bias(const float* __restrict__ rpb,
                                                 float* __restrict__ bias64) {
    int tid = blockIdx.x * 256 + threadIdx.x;  // 12*64*64 = 49152
    if (tid >= 49152) return;
    int h = tid >> 12;
    int rem = tid & 4095;
    int i = rem >> 6, kk = rem & 63;
    int j = 63 - kk;
    int ridx = 15 * (i >> 3) + (i & 7) + 15 * (j >> 3) + (j & 7);
    bias64[tid] = rpb[ridx * 12 + h];
}

// ---------------- gemm_qkv ----------------
// A rows gathered through the shifted-window permutation, converted fp32->bf16
// in staging. n-blocks 0..2 -> k, 3..5 -> v, 6..8 -> q (A source = skip_query).
__global__ __launch_bounds__(256) void gemm_qkv(
    const float* __restrict__ xq, const float* __restrict__ xs,
    const short* __restrict__ Wt,
    const float* __restrict__ bqkv, const float* __restrict__ bskip,
    short* __restrict__ kbuf, short* __restrict__ vtbuf, short* __restrict__ qbuf) {
    __shared__ short smem[18432];  // 36864 B: lA(8K) + lB(8K) during loop; 4x9216B Lst in v-epilogue
    short(*lA)[32] = (short(*)[32])smem;
    short(*lB)[32] = (short(*)[32])(smem + 4096);

    int bid = blockIdx.x;
    int per = gridDim.x >> 3;  // grid % 8 == 0
    int lb = (bid & 7) * per + (bid >> 3);  // XCD-contiguous remap
    int mblk = lb / 9, nb = lb % 9;
    int m0 = mblk * 128, n0 = nb * 128;
    const float* src = (nb < 6) ? xq : xs;

    int tid = threadIdx.x;
    int lane = tid & 63, wid = tid >> 6;
    int l15 = lane & 15, g4 = lane >> 4;

    const float* aptr[2];
    const short* bptr[2];
    short* awr[2];
    short* bwr[2];
#pragma unroll
    for (int i = 0; i < 2; i++) {
        int cid = tid + 256 * i;
        int row = cid >> 2, slot = cid & 3;
        int g = m0 + row;
        int win = g >> 6, t = g & 63;
        int b = win / 144, wr = win % 144;
        int wy = wr / 12, wx = wr % 12;
        int yy = wy * 8 + (t >> 3) + 4; if (yy >= 96) yy -= 96;
        int xx = wx * 8 + (t & 7) + 4;  if (xx >= 96) xx -= 96;
        aptr[i] = src + ((size_t)b * 9216 + yy * 96 + xx) * 384 + slot * 8;
        bptr[i] = Wt + (size_t)(n0 + row) * 384 + slot * 8;
        awr[i] = &lA[row][slot * 8];
        bwr[i] = &lB[row][slot * 8];
    }

    floatx4 acc[4][4];
#pragma unroll
    for (int mi = 0; mi < 4; mi++)
#pragma unroll
        for (int nj = 0; nj < 4; nj++)
#pragma unroll
            for (int r = 0; r < 4; r++) acc[mi][nj][r] = 0.f;

    int wm = wid >> 1, wn = wid & 1;

    for (int k0 = 0; k0 < 384; k0 += 32) {
        __syncthreads();
#pragma unroll
        for (int i = 0; i < 2; i++) {
            const float* p = aptr[i] + k0;
            float4 f0 = *(const float4*)p;
            float4 f1 = *(const float4*)(p + 4);
            short8 av;
            av[0] = f2bf(f0.x); av[1] = f2bf(f0.y); av[2] = f2bf(f0.z); av[3] = f2bf(f0.w);
            av[4] = f2bf(f1.x); av[5] = f2bf(f1.y); av[6] = f2bf(f1.z); av[7] = f2bf(f1.w);
            *(short8*)awr[i] = av;
            *(short8*)bwr[i] = *(const short8*)(bptr[i] + k0);
        }
        __syncthreads();
        short8 af[4], bfr[4];
#pragma unroll
        for (int mi = 0; mi < 4; mi++)
            af[mi] = *(const short8*)(&lA[wm * 64 + mi * 16 + l15][g4 * 8]);
#pragma unroll
        for (int nj = 0; nj < 4; nj++)
            bfr[nj] = *(const short8*)(&lB[wn * 64 + nj * 16 + l15][g4 * 8]);
#pragma unroll
        for (int mi = 0; mi < 4; mi++)
#pragma unroll
            for (int nj = 0; nj < 4; nj++)
                acc[mi][nj] = MFMA16(af[mi], bfr[nj], acc[mi][nj]);
    }

    // ---- epilogue ----
    int winA = (m0 + wm * 64) >> 6;   // one window per wave (64 rows)
    int ncol0 = n0 + wn * 64;

    if (nb < 3 || nb >= 6) {
        // k or q: direct scatter, row-major [win,head][t][d]
        short* buf;
        const float* bias;
        float scl;
        if (nb < 3) { buf = kbuf; bias = bqkv; scl = 1.0f; }
        else        { buf = qbuf; bias = bskip - 768; scl = 0.17677669529663687f; }  // HD^-0.5
#pragma unroll
        for (int nj = 0; nj < 4; nj++) {
            int n = ncol0 + nj * 16 + l15;
            float bv = bias[n];
            int nm = (n >= 768) ? (n - 768) : n;
            int head = nm >> 5, d = nm & 31;
            short* dst = buf + (size_t)(winA * 12 + head) * 2048 + d;
#pragma unroll
            for (int mi = 0; mi < 4; mi++)
#pragma unroll
                for (int r = 0; r < 4; r++) {
                    int t = mi * 16 + g4 * 4 + r;
                    dst[(size_t)t * 32] = f2bf((acc[mi][nj][r] + bv) * scl);
                }
        }
    } else {
        // v: transpose via per-wave LDS, write [win,head][d][t]
        __syncthreads();
        short(*Lst)[72] = (short(*)[72])(smem + wid * 4608);
#pragma unroll
        for (int nj = 0; nj < 4; nj++) {
            int c = nj * 16 + l15;
            float bv = bqkv[ncol0 + c];
#pragma unroll
            for (int mi = 0; mi < 4; mi++) {
                short4v pk;
#pragma unroll
                for (int r = 0; r < 4; r++) pk[r] = f2bf(acc[mi][nj][r] + bv);
                *(short4v*)(&Lst[c][mi * 16 + g4 * 4]) = pk;
            }
        }
#pragma unroll
        for (int it = 0; it < 8; it++) {
            int c = it * 8 + (lane >> 3);
            int t0 = (lane & 7) * 8;
            short8 val = *(const short8*)(&Lst[c][t0]);
            int n = ncol0 + c - 384;
            int head = n >> 5, d = n & 31;
            *(short8*)(vtbuf + ((size_t)(winA * 12 + head) * 32 + d) * 64 + t0) = val;
        }
    }
}

// ---------------- attention ----------------
// one wave per (window, head); S^T = mfma(K, Q); softmax over keys; out^T = mfma(V^T, P^T)
__global__ __launch_bounds__(256) void attn_kernel(
    const short* __restrict__ kbuf, const short* __restrict__ vtbuf,
    const short* __restrict__ qbuf, const float* __restrict__ bias64,
    short* __restrict__ aout, int ntask) {
    __shared__ short lps[18432];  // 4 waves x 64 x 72
    int lane = threadIdx.x & 63, wid = threadIdx.x >> 6;
    int task = blockIdx.x * 4 + wid;
    if (task >= ntask) return;
    int win = task / 12, head = task % 12;
    int l15 = lane & 15, g4 = lane >> 4;

    const short* kb = kbuf + (size_t)task * 2048;
    const short* qb = qbuf + (size_t)task * 2048;
    const short* vb = vtbuf + (size_t)task * 2048;

    short8 kf[4], qf[4], vf[2][2];
#pragma unroll
    for (int mi = 0; mi < 4; mi++)
        kf[mi] = *(const short8*)(kb + (mi * 16 + l15) * 32 + g4 * 8);
#pragma unroll
    for (int nj = 0; nj < 4; nj++)
        qf[nj] = *(const short8*)(qb + (nj * 16 + l15) * 32 + g4 * 8);
#pragma unroll
    for (int ma = 0; ma < 2; ma++)
#pragma unroll
        for (int ks = 0; ks < 2; ks++)
            vf[ma][ks] = *(const short8*)(vb + (ma * 16 + l15) * 64 + ks * 32 + g4 * 8);

    floatx4 st[4][4];
#pragma unroll
    for (int mi = 0; mi < 4; mi++)
#pragma unroll
        for (int nj = 0; nj < 4; nj++)
#pragma unroll
            for (int r = 0; r < 4; r++) st[mi][nj][r] = 0.f;

#pragma unroll
    for (int mi = 0; mi < 4; mi++)
#pragma unroll
        for (int nj = 0; nj < 4; nj++)
            st[mi][nj] = MFMA16(kf[mi], qf[nj], st[mi][nj]);  // S^T[kk][i]

    // relative-position bias
    const float* bb = bias64 + head * 4096;
#pragma unroll
    for (int nj = 0; nj < 4; nj++) {
        int i = nj * 16 + l15;
#pragma unroll
        for (int mi = 0; mi < 4; mi++) {
            floatx4 b4 = *(const floatx4*)(bb + i * 64 + mi * 16 + g4 * 4);
            st[mi][nj] += b4;
        }
    }

    // shifted-window mask (only last window row/col of each image)
    int wr = win % 144;
    int wy = wr / 12, wx = wr % 12;
    if (wy == 11 || wx == 11) {
        int wy11 = (wy == 11), wx11 = (wx == 11);
        int ri[4];
#pragma unroll
        for (int nj = 0; nj < 4; nj++) {
            int t = nj * 16 + l15;
            int hh = wy11 ? (((t >> 3) >= 4) ? 2 : 1) : 0;
            int ww = wx11 ? (((t & 7) >= 4) ? 2 : 1) : 0;
            ri[nj] = hh * 3 + ww;
        }
#pragma unroll
        for (int mi = 0; mi < 4; mi++)
#pragma unroll
            for (int r = 0; r < 4; r++) {
                int t = mi * 16 + g4 * 4 + r;
                int hh = wy11 ? (((t >> 3) >= 4) ? 2 : 1) : 0;
                int ww = wx11 ? (((t & 7) >= 4) ? 2 : 1) : 0;
                int rk = hh * 3 + ww;
#pragma unroll
                for (int nj = 0; nj < 4; nj++)
                    if (rk != ri[nj]) st[mi][nj][r] -= 100.0f;
            }
    }

    // softmax over kk (rows of S^T) for each column i
    float rden[4];
#pragma unroll
    for (int nj = 0; nj < 4; nj++) {
        float m = -1e30f;
#pragma unroll
        for (int mi = 0; mi < 4; mi++)
#pragma unroll
            for (int r = 0; r < 4; r++) m = fmaxf(m, st[mi][nj][r]);
        m = fmaxf(m, __shfl_xor(m, 16));
        m = fmaxf(m, __shfl_xor(m, 32));
        float s = 0.f;
#pragma unroll
        for (int mi = 0; mi < 4; mi++)
#pragma unroll
            for (int r = 0; r < 4; r++) {
                float p = __expf(st[mi][nj][r] - m);
                st[mi][nj][r] = p;
                s += p;
            }
        s += __shfl_xor(s, 16);
        s += __shfl_xor(s, 32);
        rden[nj] = 1.0f / s;
    }

    // P^T -> LDS (bf16, packed 4 along kk)
    short(*Lp)[72] = (short(*)[72])(lps + wid * 4608);
#pragma unroll
    for (int mi = 0; mi < 4; mi++)
#pragma unroll
        for (int nj = 0; nj < 4; nj++) {
            short4v pk;
#pragma unroll
            for (int r = 0; r < 4; r++) pk[r] = f2bf(st[mi][nj][r]);
            *(short4v*)(&Lp[nj * 16 + l15][mi * 16 + g4 * 4]) = pk;
        }

    // out^T = V^T @ P^T
    floatx4 o[2][4];
#pragma unroll
    for (int ma = 0; ma < 2; ma++)
#pragma unroll
        for (int nj = 0; nj < 4; nj++)
#pragma unroll
            for (int r = 0; r < 4; r++) o[ma][nj][r] = 0.f;
#pragma unroll
    for (int ks = 0; ks < 2; ks++) {
        short8 pb[4];
#pragma unroll
        for (int nj = 0; nj < 4; nj++)
            pb[nj] = *(const short8*)(&Lp[nj * 16 + l15][ks * 32 + g4 * 8]);
#pragma unroll
        for (int ma = 0; ma < 2; ma++)
#pragma unroll
            for (int nj = 0; nj < 4; nj++)
                o[ma][nj] = MFMA16(vf[ma][ks], pb[nj], o[ma][nj]);
    }

    // store out[i][head*32+d] as bf16 row-major tokens x C
    short* ob = aout + (size_t)win * 64 * 384 + head * 32;
#pragma unroll
    for (int ma = 0; ma < 2; ma++)
#pragma unroll
        for (int nj = 0; nj < 4; nj++) {
            int i = nj * 16 + l15;
            short4v pk;
#pragma unroll
            for (int r = 0; r < 4; r++) pk[r] = f2bf(o[ma][nj][r] * rden[nj]);
            *(short4v*)(ob + (size_t)i * 384 + ma * 16 + g4 * 4) = pk;
        }
}

// ---------------- gemm_proj ----------------
__global__ __launch_bounds__(256) void gemm_proj(
    const short* __restrict__ aout, const short* __restrict__ WtP,
    const float* __restrict__ bproj, float* __restrict__ out) {
    __shared__ short smem[8192];
    short(*lA)[32] = (short(*)[32])smem;
    short(*lB)[32] = (short(*)[32])(smem + 4096);

    int bid = blockIdx.x;
    int per = gridDim.x >> 3;
    int lb = (bid & 7) * per + (bid >> 3);
    int mblk = lb / 3, nb = lb % 3;
    int m0 = mblk * 128, n0 = nb * 128;

    int tid = threadIdx.x;
    int lane = tid & 63, wid = tid >> 6;
    int l15 = lane & 15, g4 = lane >> 4;

    const short* aptr[2];
    const short* bptr[2];
    short* awr[2];
    short* bwr[2];
#pragma unroll
    for (int i = 0; i < 2; i++) {
        int cid = tid + 256 * i;
        int row = cid >> 2, slot = cid & 3;
        aptr[i] = aout + (size_t)(m0 + row) * 384 + slot * 8;
        bptr[i] = WtP + (size_t)(n0 + row) * 384 + slot * 8;
        awr[i] = &lA[row][slot * 8];
        bwr[i] = &lB[row][slot * 8];
    }

    floatx4 acc[4][4];
#pragma unroll
    for (int mi = 0; mi < 4; mi++)
#pragma unroll
        for (int nj = 0; nj < 4; nj++)
#pragma unroll
            for (int r = 0; r < 4; r++) acc[mi][nj][r] = 0.f;

    int wm = wid >> 1, wn = wid & 1;

    for (int k0 = 0; k0 < 384; k0 += 32) {
        __syncthreads();
#pragma unroll
        for (int i = 0; i < 2; i++) {
            *(short8*)awr[i] = *(const short8*)(aptr[i] + k0);
            *(short8*)bwr[i] = *(const short8*)(bptr[i] + k0);
        }
        __syncthreads();
        short8 af[4], bfr[4];
#pragma unroll
        for (int mi = 0; mi < 4; mi++)
            af[mi] = *(const short8*)(&lA[wm * 64 + mi * 16 + l15][g4 * 8]);
#pragma unroll
        for (int nj = 0; nj < 4; nj++)
            bfr[nj] = *(const short8*)(&lB[wn * 64 + nj * 16 + l15][g4 * 8]);
#pragma unroll
        for (int mi = 0; mi < 4; mi++)
#pragma unroll
            for (int nj = 0; nj < 4; nj++)
                acc[mi][nj] = MFMA16(af[mi], bfr[nj], acc[mi][nj]);
    }

    // epilogue: + bias, inverse shift-window scatter, fp32
    int winA = (m0 + wm * 64) >> 6;
    int b_img = winA / 144, wr = winA % 144;
    int wy = wr / 12, wx = wr % 12;
#pragma unroll
    for (int nj = 0; nj < 4; nj++) {
        int n = n0 + wn * 64 + nj * 16 + l15;
        float bv = bproj[n];
#pragma unroll
        for (int mi = 0; mi < 4; mi++)
#pragma unroll
            for (int r = 0; r < 4; r++) {
                int t = mi * 16 + g4 * 4 + r;
                int yy = wy * 8 + (t >> 3) + 4; if (yy >= 96) yy -= 96;
                int xx = wx * 8 + (t & 7) + 4;  if (xx >= 96) xx -= 96;
                out[((size_t)b_img * 9216 + yy * 96 + xx) * 384 + n] = acc[mi][nj][r] + bv;
            }
    }
}

// ---------------- launcher ----------------
extern "C" void kernel_launch(void* const* d_in, const int* in_sizes, int n_in,
                              void* d_out, int out_size, void* d_ws, size_t ws_size,
                              hipStream_t stream) {
    const float* query = (const float*)d_in[0];
    const float* skipq = (const float*)d_in[1];
    const float* Wqkv  = (const float*)d_in[2];
    const float* bqkv  = (const float*)d_in[3];
    const float* Wskip = (const float*)d_in[4];
    const float* bskip = (const float*)d_in[5];
    const float* rpb   = (const float*)d_in[6];
    const float* Wproj = (const float*)d_in[7];
    const float* bproj = (const float*)d_in[8];
    float* out = (float*)d_out;

    int M = in_sizes[0] / 384;   // total tokens (B*96*96) = 147456 for B=16
    int nwin = M / 64;           // 2304
    int mblocks = M / 128;       // 1152

    char* ws = (char*)d_ws;
    size_t off = 0;
    auto alloc = [&](size_t bytes) -> void* {
        void* p = ws + off;
        off = (off + bytes + 255) & ~(size_t)255;
        return p;
    };
    short* Wt     = (short*)alloc((size_t)1152 * 384 * 2);
    short* WtP    = (short*)alloc((size_t)384 * 384 * 2);
    float* bias64 = (float*)alloc((size_t)12 * 64 * 64 * 4);
    short* kbuf   = (short*)alloc((size_t)M * 384 * 2);
    short* vtbuf  = (short*)alloc((size_t)M * 384 * 2);
    short* qbuf   = (short*)alloc((size_t)M * 384 * 2);
    short* aout   = (short*)alloc((size_t)M * 384 * 2);
    (void)ws_size;

    hipLaunchKernelGGL(prep_wt, dim3(216), dim3(256), 0, stream, Wqkv, Wskip, Wt);
    hipLaunchKernelGGL(prep_wtp, dim3(72), dim3(256), 0, stream, Wproj, WtP);
    hipLaunchKernelGGL(prep_bias, dim3(192), dim3(256), 0, stream, rpb, bias64);
    hipLaunchKernelGGL(gemm_qkv, dim3(mblocks * 9), dim3(256), 0, stream,
                       query, skipq, Wt, bqkv, bskip, kbuf, vtbuf, qbuf);
    hipLaunchKernelGGL(attn_kernel, dim3(nwin * 12 / 4), dim3(256), 0, stream,
                       kbuf, vtbuf, qbuf, bias64, aout, nwin * 12);
    hipLaunchKernelGGL(gemm_proj, dim3(mblocks * 3), dim3(256), 0, stream,
                       aout, WtP, bproj, out);
}

// Round 4
// 594.346 us; speedup vs baseline: 1.0620x; 1.0620x over previous
//
#include <hip/hip_runtime.h>
#include <hip/hip_bf16.h>

// ShiftWindowMSA fused pipeline for MI355X (gfx950).
// R4: R3 with the LDS XOR swizzle fixed to a bijective 2-bit form:
// phys_chunk = logical_chunk ^ ((row ^ (row>>2)) & 3), applied on A's LDS
// write, B's pre-swizzled global source, and the fragment reads.

typedef __attribute__((ext_vector_type(8))) short short8;
typedef __attribute__((ext_vector_type(4))) short short4v;
typedef __attribute__((ext_vector_type(4))) float floatx4;

#define MFMA16(a, b, c) __builtin_amdgcn_mfma_f32_16x16x32_bf16(a, b, c, 0, 0, 0)

__device__ __forceinline__ short f2bf(float f) {
    __hip_bfloat16 h = __float2bfloat16(f);
    return *reinterpret_cast<short*>(&h);
}

__device__ __forceinline__ void glds16(const void* g, void* l) {
    __builtin_amdgcn_global_load_lds(
        (const __attribute__((address_space(1))) void*)g,
        (__attribute__((address_space(3))) void*)l, 16, 0, 0);
}

// ---------------- prep kernels ----------------

// Wt[1152][384] bf16: rows 0..767 = columns of W_qkv (384x768); 768.. = columns of W_skip (384x384)
__global__ __launch_bounds__(256) void prep_wt(const float* __restrict__ Wqkv,
                                               const float* __restrict__ Wskip,
                                               short* __restrict__ Wt) {
    int tid = blockIdx.x * 256 + threadIdx.x;  // 384*144 = 55296
    if (tid >= 384 * 144) return;
    int k = tid / 144;
    int n8 = (tid % 144) * 8;
#pragma unroll
    for (int e = 0; e < 8; e++) {
        int n = n8 + e;
        float v = (n < 768) ? Wqkv[k * 768 + n] : Wskip[k * 384 + (n - 768)];
        Wt[(size_t)n * 384 + k] = f2bf(v);
    }
}

__global__ __launch_bounds__(256) void prep_wtp(const float* __restrict__ Wproj,
                                                short* __restrict__ WtP) {
    int tid = blockIdx.x * 256 + threadIdx.x;  // 384*48 = 18432
    if (tid >= 384 * 48) return;
    int k = tid / 48;
    int n8 = (tid % 48) * 8;
#pragma unroll
    for (int e = 0; e < 8; e++) {
        int n = n8 + e;
        WtP[(size_t)n * 384 + k] = f2bf(Wproj[k * 384 + n]);
    }
}

// bias64[h][i][kk] = rpb_table[r(i) + r(63-kk)][h],  r(t) = 15*(t>>3) + (t&7)
__global__ __launch_bounds__(256) void prep_bias(const float* __restrict__ rpb,
                                                 float* __restrict__ bias64) {
    int tid = blockIdx.x * 256 + threadIdx.x;  // 12*64*64 = 49152
    if (tid >= 49152) return;
    int h = tid >> 12;
    int rem = tid & 4095;
    int i = rem >> 6, kk = rem & 63;
    int j = 63 - kk;
    int ridx = 15 * (i >> 3) + (i & 7) + 15 * (j >> 3) + (j & 7);
    bias64[tid] = rpb[ridx * 12 + h];
}

// ---------------- gemm_qkv ----------------
// A rows gathered through the shifted-window permutation, converted fp32->bf16
// in reg staging. n-blocks 0..2 -> k, 3..5 -> v, 6..8 -> q (A source = skip_query).
// Double-buffered LDS via integer offsets, 1 barrier / K-step, 2-bit XOR swizzle.
__global__ __launch_bounds__(256) void gemm_qkv(
    const float* __restrict__ xq, const float* __restrict__ xs,
    const short* __restrict__ Wt,
    const float* __restrict__ bqkv, const float* __restrict__ bskip,
    short* __restrict__ kbuf, short* __restrict__ vtbuf, short* __restrict__ qbuf) {
    __shared__ short smem[18432];  // A: [0,4096)+[4096,8192), B: [8192,12288)+[12288,16384)

    int bid = blockIdx.x;
    int per = gridDim.x >> 3;               // grid % 8 == 0
    int lb = (bid & 7) * per + (bid >> 3);  // XCD-contiguous remap
    int mblk = lb / 9, nb = lb % 9;
    int m0 = mblk * 128, n0 = nb * 128;
    const float* src = (nb < 6) ? xq : xs;

    int tid = threadIdx.x;
    int lane = tid & 63, wid = tid >> 6;
    int l15 = lane & 15, g4 = lane >> 4;
    int wm = wid >> 1, wn = wid & 1;

    // A staging roles: thread handles 2 chunks (row, slot), slot = 8 fp32 -> 8 bf16
    const float* aptr[2];
    int awoff[2];
#pragma unroll
    for (int i = 0; i < 2; i++) {
        int cid = tid + 256 * i;
        int row = cid >> 2, slot = cid & 3;
        int sw = (row ^ (row >> 2)) & 3;
        int g = m0 + row;
        int win = g >> 6, t = g & 63;
        int b = win / 144, wr = win % 144;
        int wy = wr / 12, wx = wr % 12;
        int yy = wy * 8 + (t >> 3) + 4; if (yy >= 96) yy -= 96;
        int xx = wx * 8 + (t & 7) + 4;  if (xx >= 96) xx -= 96;
        aptr[i] = src + ((size_t)b * 9216 + yy * 96 + xx) * 384 + slot * 8;
        awoff[i] = row * 32 + ((slot ^ sw) * 8);
    }

    // B gload_lds roles: per wave 2 issues of 64 lanes x 16B; pre-swizzled global addr
    const short* bg[2];
    int bldsoff[2];
#pragma unroll
    for (int j = 0; j < 2; j++) {
        int c0 = wid * 128 + j * 64;
        int c = c0 + lane;
        int brow = c >> 2, bs = c & 3;
        int sw = (brow ^ (brow >> 2)) & 3;
        bg[j] = Wt + (size_t)(n0 + brow) * 384 + ((bs ^ sw) * 8);
        bldsoff[j] = 8192 + c0 * 8;  // wave-uniform LDS chunk base (shorts)
    }

    // fragment read offsets (swizzled): row = ..+l15, sw(row) = (l15^(l15>>2))&3
    int swr = (l15 ^ (l15 >> 2)) & 3;
    int xcol = (g4 ^ swr) * 8;
    int aro[4], bro[4];
#pragma unroll
    for (int mi = 0; mi < 4; mi++) aro[mi] = (wm * 64 + mi * 16 + l15) * 32 + xcol;
#pragma unroll
    for (int nj = 0; nj < 4; nj++) bro[nj] = 8192 + (wn * 64 + nj * 16 + l15) * 32 + xcol;

    floatx4 acc[4][4];
#pragma unroll
    for (int mi = 0; mi < 4; mi++)
#pragma unroll
        for (int nj = 0; nj < 4; nj++)
#pragma unroll
            for (int r = 0; r < 4; r++) acc[mi][nj][r] = 0.f;

    // prologue: stage k-tile 0 into buffer half 0
#pragma unroll
    for (int j = 0; j < 2; j++) glds16(bg[j], smem + bldsoff[j]);
    float4 fa[2][2];
#pragma unroll
    for (int i = 0; i < 2; i++) {
        fa[i][0] = *(const float4*)(aptr[i]);
        fa[i][1] = *(const float4*)(aptr[i] + 4);
    }
#pragma unroll
    for (int i = 0; i < 2; i++) {
        short8 av;
        av[0] = f2bf(fa[i][0].x); av[1] = f2bf(fa[i][0].y);
        av[2] = f2bf(fa[i][0].z); av[3] = f2bf(fa[i][0].w);
        av[4] = f2bf(fa[i][1].x); av[5] = f2bf(fa[i][1].y);
        av[6] = f2bf(fa[i][1].z); av[7] = f2bf(fa[i][1].w);
        *(short8*)(smem + awoff[i]) = av;
    }
    __syncthreads();  // drains vmcnt (incl. gload_lds) + lgkm

    for (int kt = 0; kt < 12; ++kt) {
        int curb = (kt & 1) * 4096;
        int nxtb = 4096 - curb;
        bool more = kt < 11;
        if (more) {
            int k0 = (kt + 1) * 32;
#pragma unroll
            for (int j = 0; j < 2; j++) glds16(bg[j] + k0, smem + nxtb + bldsoff[j]);
#pragma unroll
            for (int i = 0; i < 2; i++) {
                fa[i][0] = *(const float4*)(aptr[i] + k0);
                fa[i][1] = *(const float4*)(aptr[i] + k0 + 4);
            }
        }
        short8 af[4], bfr[4];
#pragma unroll
        for (int mi = 0; mi < 4; mi++) af[mi] = *(const short8*)(smem + curb + aro[mi]);
#pragma unroll
        for (int nj = 0; nj < 4; nj++) bfr[nj] = *(const short8*)(smem + curb + bro[nj]);
#pragma unroll
        for (int mi = 0; mi < 4; mi++)
#pragma unroll
            for (int nj = 0; nj < 4; nj++)
                acc[mi][nj] = MFMA16(af[mi], bfr[nj], acc[mi][nj]);
        if (more) {
#pragma unroll
            for (int i = 0; i < 2; i++) {
                short8 av;
                av[0] = f2bf(fa[i][0].x); av[1] = f2bf(fa[i][0].y);
                av[2] = f2bf(fa[i][0].z); av[3] = f2bf(fa[i][0].w);
                av[4] = f2bf(fa[i][1].x); av[5] = f2bf(fa[i][1].y);
                av[6] = f2bf(fa[i][1].z); av[7] = f2bf(fa[i][1].w);
                *(short8*)(smem + nxtb + awoff[i]) = av;
            }
        }
        __syncthreads();
    }

    // ---- epilogue ----
    int winA = (m0 + wm * 64) >> 6;   // one window per wave (64 rows)
    int ncol0 = n0 + wn * 64;

    if (nb < 3 || nb >= 6) {
        // k or q: direct scatter, row-major [win,head][t][d]
        short* buf;
        const float* bias;
        float scl;
        if (nb < 3) { buf = kbuf; bias = bqkv; scl = 1.0f; }
        else        { buf = qbuf; bias = bskip - 768; scl = 0.17677669529663687f; }  // HD^-0.5
#pragma unroll
        for (int nj = 0; nj < 4; nj++) {
            int n = ncol0 + nj * 16 + l15;
            float bv = bias[n];
            int nm = (n >= 768) ? (n - 768) : n;
            int head = nm >> 5, d = nm & 31;
            short* dst = buf + (size_t)(winA * 12 + head) * 2048 + d;
#pragma unroll
            for (int mi = 0; mi < 4; mi++)
#pragma unroll
                for (int r = 0; r < 4; r++) {
                    int t = mi * 16 + g4 * 4 + r;
                    dst[(size_t)t * 32] = f2bf((acc[mi][nj][r] + bv) * scl);
                }
        }
    } else {
        // v: transpose via per-wave LDS, write [win,head][d][t]
        short* Lst = smem + wid * 4608;  // [64][72]
#pragma unroll
        for (int nj = 0; nj < 4; nj++) {
            int c = nj * 16 + l15;
            float bv = bqkv[ncol0 + c];
#pragma unroll
            for (int mi = 0; mi < 4; mi++) {
                short4v pk;
#pragma unroll
                for (int r = 0; r < 4; r++) pk[r] = f2bf(acc[mi][nj][r] + bv);
                *(short4v*)(Lst + c * 72 + mi * 16 + g4 * 4) = pk;
            }
        }
#pragma unroll
        for (int it = 0; it < 8; it++) {
            int c = it * 8 + (lane >> 3);
            int t0 = (lane & 7) * 8;
            short8 val = *(const short8*)(Lst + c * 72 + t0);
            int n = ncol0 + c - 384;
            int head = n >> 5, d = n & 31;
            *(short8*)(vtbuf + ((size_t)(winA * 12 + head) * 32 + d) * 64 + t0) = val;
        }
    }
}

// ---------------- attention ----------------
// one wave per (window, head); S^T = mfma(K, Q); softmax over keys; out^T = mfma(V^T, P^T)
__global__ __launch_bounds__(256) void attn_kernel(
    const short* __restrict__ kbuf, const short* __restrict__ vtbuf,
    const short* __restrict__ qbuf, const float* __restrict__ bias64,
    short* __restrict__ aout, int ntask) {
    __shared__ short lps[18432];  // 4 waves x 64 x 72
    int lane = threadIdx.x & 63, wid = threadIdx.x >> 6;
    int task = blockIdx.x * 4 + wid;
    if (task >= ntask) return;
    int win = task / 12, head = task % 12;
    int l15 = lane & 15, g4 = lane >> 4;

    const short* kb = kbuf + (size_t)task * 2048;
    const short* qb = qbuf + (size_t)task * 2048;
    const short* vb = vtbuf + (size_t)task * 2048;

    short8 kf[4], qf[4], vf[2][2];
#pragma unroll
    for (int mi = 0; mi < 4; mi++)
        kf[mi] = *(const short8*)(kb + (mi * 16 + l15) * 32 + g4 * 8);
#pragma unroll
    for (int nj = 0; nj < 4; nj++)
        qf[nj] = *(const short8*)(qb + (nj * 16 + l15) * 32 + g4 * 8);
#pragma unroll
    for (int ma = 0; ma < 2; ma++)
#pragma unroll
        for (int ks = 0; ks < 2; ks++)
            vf[ma][ks] = *(const short8*)(vb + (ma * 16 + l15) * 64 + ks * 32 + g4 * 8);

    floatx4 st[4][4];
#pragma unroll
    for (int mi = 0; mi < 4; mi++)
#pragma unroll
        for (int nj = 0; nj < 4; nj++)
#pragma unroll
            for (int r = 0; r < 4; r++) st[mi][nj][r] = 0.f;

#pragma unroll
    for (int mi = 0; mi < 4; mi++)
#pragma unroll
        for (int nj = 0; nj < 4; nj++)
            st[mi][nj] = MFMA16(kf[mi], qf[nj], st[mi][nj]);  // S^T[kk][i]

    // relative-position bias
    const float* bb = bias64 + head * 4096;
#pragma unroll
    for (int nj = 0; nj < 4; nj++) {
        int i = nj * 16 + l15;
#pragma unroll
        for (int mi = 0; mi < 4; mi++) {
            floatx4 b4 = *(const floatx4*)(bb + i * 64 + mi * 16 + g4 * 4);
            st[mi][nj] += b4;
        }
    }

    // shifted-window mask (only last window row/col of each image)
    int wr = win % 144;
    int wy = wr / 12, wx = wr % 12;
    if (wy == 11 || wx == 11) {
        int wy11 = (wy == 11), wx11 = (wx == 11);
        int ri[4];
#pragma unroll
        for (int nj = 0; nj < 4; nj++) {
            int t = nj * 16 + l15;
            int hh = wy11 ? (((t >> 3) >= 4) ? 2 : 1) : 0;
            int ww = wx11 ? (((t & 7) >= 4) ? 2 : 1) : 0;
            ri[nj] = hh * 3 + ww;
        }
#pragma unroll
        for (int mi = 0; mi < 4; mi++)
#pragma unroll
            for (int r = 0; r < 4; r++) {
                int t = mi * 16 + g4 * 4 + r;
                int hh = wy11 ? (((t >> 3) >= 4) ? 2 : 1) : 0;
                int ww = wx11 ? (((t & 7) >= 4) ? 2 : 1) : 0;
                int rk = hh * 3 + ww;
#pragma unroll
                for (int nj = 0; nj < 4; nj++)
                    if (rk != ri[nj]) st[mi][nj][r] -= 100.0f;
            }
    }

    // softmax over kk (rows of S^T) for each column i
    float rden[4];
#pragma unroll
    for (int nj = 0; nj < 4; nj++) {
        float m = -1e30f;
#pragma unroll
        for (int mi = 0; mi < 4; mi++)
#pragma unroll
            for (int r = 0; r < 4; r++) m = fmaxf(m, st[mi][nj][r]);
        m = fmaxf(m, __shfl_xor(m, 16));
        m = fmaxf(m, __shfl_xor(m, 32));
        float s = 0.f;
#pragma unroll
        for (int mi = 0; mi < 4; mi++)
#pragma unroll
            for (int r = 0; r < 4; r++) {
                float p = __expf(st[mi][nj][r] - m);
                st[mi][nj][r] = p;
                s += p;
            }
        s += __shfl_xor(s, 16);
        s += __shfl_xor(s, 32);
        rden[nj] = 1.0f / s;
    }

    // P^T -> LDS (bf16, packed 4 along kk)
    short* Lp = lps + wid * 4608;  // [64][72]
#pragma unroll
    for (int mi = 0; mi < 4; mi++)
#pragma unroll
        for (int nj = 0; nj < 4; nj++) {
            short4v pk;
#pragma unroll
            for (int r = 0; r < 4; r++) pk[r] = f2bf(st[mi][nj][r]);
            *(short4v*)(Lp + (nj * 16 + l15) * 72 + mi * 16 + g4 * 4) = pk;
        }

    // out^T = V^T @ P^T
    floatx4 o[2][4];
#pragma unroll
    for (int ma = 0; ma < 2; ma++)
#pragma unroll
        for (int nj = 0; nj < 4; nj++)
#pragma unroll
            for (int r = 0; r < 4; r++) o[ma][nj][r] = 0.f;
#pragma unroll
    for (int ks = 0; ks < 2; ks++) {
        short8 pb[4];
#pragma unroll
        for (int nj = 0; nj < 4; nj++)
            pb[nj] = *(const short8*)(Lp + (nj * 16 + l15) * 72 + ks * 32 + g4 * 8);
#pragma unroll
        for (int ma = 0; ma < 2; ma++)
#pragma unroll
            for (int nj = 0; nj < 4; nj++)
                o[ma][nj] = MFMA16(vf[ma][ks], pb[nj], o[ma][nj]);
    }

    // store out[i][head*32+d] as bf16 row-major tokens x C
    short* ob = aout + (size_t)win * 64 * 384 + head * 32;
#pragma unroll
    for (int ma = 0; ma < 2; ma++)
#pragma unroll
        for (int nj = 0; nj < 4; nj++) {
            int i = nj * 16 + l15;
            short4v pk;
#pragma unroll
            for (int r = 0; r < 4; r++) pk[r] = f2bf(o[ma][nj][r] * rden[nj]);
            *(short4v*)(ob + (size_t)i * 384 + ma * 16 + g4 * 4) = pk;
        }
}

// ---------------- gemm_proj ----------------
// Both operands bf16 row-major -> global_load_lds with pre-swizzled source addrs.
__global__ __launch_bounds__(256) void gemm_proj(
    const short* __restrict__ aout, const short* __restrict__ WtP,
    const float* __restrict__ bproj, float* __restrict__ out) {
    __shared__ short smem[16384];  // A: [0,4096)+[4096,8192), B: +8192

    int bid = blockIdx.x;
    int per = gridDim.x >> 3;
    int lb = (bid & 7) * per + (bid >> 3);
    int mblk = lb / 3, nb = lb % 3;
    int m0 = mblk * 128, n0 = nb * 128;

    int tid = threadIdx.x;
    int lane = tid & 63, wid = tid >> 6;
    int l15 = lane & 15, g4 = lane >> 4;
    int wm = wid >> 1, wn = wid & 1;

    const short* ag[2];
    const short* bg[2];
    int ldso[2];
#pragma unroll
    for (int j = 0; j < 2; j++) {
        int c0 = wid * 128 + j * 64;
        int c = c0 + lane;
        int row = c >> 2, s = c & 3;
        int sw = (row ^ (row >> 2)) & 3;
        int co = (s ^ sw) * 8;
        ag[j] = aout + (size_t)(m0 + row) * 384 + co;
        bg[j] = WtP + (size_t)(n0 + row) * 384 + co;
        ldso[j] = c0 * 8;
    }

    int swr = (l15 ^ (l15 >> 2)) & 3;
    int xcol = (g4 ^ swr) * 8;
    int aro[4], bro[4];
#pragma unroll
    for (int mi = 0; mi < 4; mi++) aro[mi] = (wm * 64 + mi * 16 + l15) * 32 + xcol;
#pragma unroll
    for (int nj = 0; nj < 4; nj++) bro[nj] = 8192 + (wn * 64 + nj * 16 + l15) * 32 + xcol;

    floatx4 acc[4][4];
#pragma unroll
    for (int mi = 0; mi < 4; mi++)
#pragma unroll
        for (int nj = 0; nj < 4; nj++)
#pragma unroll
            for (int r = 0; r < 4; r++) acc[mi][nj][r] = 0.f;

#pragma unroll
    for (int j = 0; j < 2; j++) {
        glds16(ag[j], smem + ldso[j]);
        glds16(bg[j], smem + 8192 + ldso[j]);
    }
    __syncthreads();

    for (int kt = 0; kt < 12; ++kt) {
        int curb = (kt & 1) * 4096;
        int nxtb = 4096 - curb;
        if (kt < 11) {
            int k0 = (kt + 1) * 32;
#pragma unroll
            for (int j = 0; j < 2; j++) {
                glds16(ag[j] + k0, smem + nxtb + ldso[j]);
                glds16(bg[j] + k0, smem + 8192 + nxtb + ldso[j]);
            }
        }
        short8 af[4], bfr[4];
#pragma unroll
        for (int mi = 0; mi < 4; mi++) af[mi] = *(const short8*)(smem + curb + aro[mi]);
#pragma unroll
        for (int nj = 0; nj < 4; nj++) bfr[nj] = *(const short8*)(smem + curb + bro[nj]);
#pragma unroll
        for (int mi = 0; mi < 4; mi++)
#pragma unroll
            for (int nj = 0; nj < 4; nj++)
                acc[mi][nj] = MFMA16(af[mi], bfr[nj], acc[mi][nj]);
        __syncthreads();
    }

    // epilogue: + bias, inverse shift-window scatter, fp32
    int winA = (m0 + wm * 64) >> 6;
    int b_img = winA / 144, wr = winA % 144;
    int wy = wr / 12, wx = wr % 12;
#pragma unroll
    for (int nj = 0; nj < 4; nj++) {
        int n = n0 + wn * 64 + nj * 16 + l15;
        float bv = bproj[n];
#pragma unroll
        for (int mi = 0; mi < 4; mi++)
#pragma unroll
            for (int r = 0; r < 4; r++) {
                int t = mi * 16 + g4 * 4 + r;
                int yy = wy * 8 + (t >> 3) + 4; if (yy >= 96) yy -= 96;
                int xx = wx * 8 + (t & 7) + 4;  if (xx >= 96) xx -= 96;
                out[((size_t)b_img * 9216 + yy * 96 + xx) * 384 + n] = acc[mi][nj][r] + bv;
            }
    }
}

// ---------------- launcher ----------------
extern "C" void kernel_launch(void* const* d_in, const int* in_sizes, int n_in,
                              void* d_out, int out_size, void* d_ws, size_t ws_size,
                              hipStream_t stream) {
    const float* query = (const float*)d_in[0];
    const float* skipq = (const float*)d_in[1];
    const float* Wqkv  = (const float*)d_in[2];
    const float* bqkv  = (const float*)d_in[3];
    const float* Wskip = (const float*)d_in[4];
    const float* bskip = (const float*)d_in[5];
    const float* rpb   = (const float*)d_in[6];
    const float* Wproj = (const float*)d_in[7];
    const float* bproj = (const float*)d_in[8];
    float* out = (float*)d_out;

    int M = in_sizes[0] / 384;   // total tokens (B*96*96) = 147456 for B=16
    int nwin = M / 64;           // 2304
    int mblocks = M / 128;       // 1152

    char* ws = (char*)d_ws;
    size_t off = 0;
    auto alloc = [&](size_t bytes) -> void* {
        void* p = ws + off;
        off = (off + bytes + 255) & ~(size_t)255;
        return p;
    };
    short* Wt     = (short*)alloc((size_t)1152 * 384 * 2);
    short* WtP    = (short*)alloc((size_t)384 * 384 * 2);
    float* bias64 = (float*)alloc((size_t)12 * 64 * 64 * 4);
    short* kbuf   = (short*)alloc((size_t)M * 384 * 2);
    short* vtbuf  = (short*)alloc((size_t)M * 384 * 2);
    short* qbuf   = (short*)alloc((size_t)M * 384 * 2);
    short* aout   = (short*)alloc((size_t)M * 384 * 2);
    (void)ws_size;

    hipLaunchKernelGGL(prep_wt, dim3(216), dim3(256), 0, stream, Wqkv, Wskip, Wt);
    hipLaunchKernelGGL(prep_wtp, dim3(72), dim3(256), 0, stream, Wproj, WtP);
    hipLaunchKernelGGL(prep_bias, dim3(192), dim3(256), 0, stream, rpb, bias64);
    hipLaunchKernelGGL(gemm_qkv, dim3(mblocks * 9), dim3(256), 0, stream,
                       query, skipq, Wt, bqkv, bskip, kbuf, vtbuf, qbuf);
    hipLaunchKernelGGL(attn_kernel, dim3(nwin * 12 / 4), dim3(256), 0, stream,
                       kbuf, vtbuf, qbuf, bias64, aout, nwin * 12);
    hipLaunchKernelGGL(gemm_proj, dim3(mblocks * 3), dim3(256), 0, stream,
                       aout, WtP, bproj, out);
}